// Round 1
// baseline (498.068 us; speedup 1.0000x reference)
//
#include <hip/hip_runtime.h>
#include <hip/hip_bf16.h>
#include <cstdint>
#include <cstddef>

#define T_TOK 2048
#define DIM   1024
#define FDIM  2048
#define NEXP  8
#define BSTRIDE 40   // LDS row stride (bf16 elems) for 32-k tiles, padded to dodge bank conflicts

typedef short  short8  __attribute__((ext_vector_type(8)));
typedef float  floatx4 __attribute__((ext_vector_type(4)));

__device__ inline unsigned short f2bf(float f) {
    unsigned int u = __builtin_bit_cast(unsigned int, f);
    unsigned int r = (u + 0x7FFFu + ((u >> 16) & 1u)) >> 16;  // RNE, no NaN path needed
    return (unsigned short)r;
}

// ---------------- Kernel 1: router + bf16 prep ----------------
// One wave per token: 8 logits, top-1, sigmoid; append token to its expert's
// list; write hb = bf16(h) and xb = bf16(score*h).
__global__ __launch_bounds__(256) void k_router(
    const float* __restrict__ h, const float* __restrict__ rw,
    int* __restrict__ counts, int* __restrict__ lists,
    unsigned short* __restrict__ hb, unsigned short* __restrict__ xb)
{
    int w = threadIdx.x >> 6, lane = threadIdx.x & 63;
    int t = blockIdx.x * 4 + w;
    const float* hrow = h + (size_t)t * DIM;
    float hv[16];
    #pragma unroll
    for (int i = 0; i < 16; ++i) hv[i] = hrow[lane + 64 * i];
    float acc[NEXP];
    #pragma unroll
    for (int e = 0; e < NEXP; ++e) {
        const float* r = rw + (size_t)e * DIM;
        float s = 0.f;
        #pragma unroll
        for (int i = 0; i < 16; ++i) s += hv[i] * r[lane + 64 * i];
        acc[e] = s;
    }
    #pragma unroll
    for (int e = 0; e < NEXP; ++e) {
        float s = acc[e];
        for (int off = 32; off > 0; off >>= 1) s += __shfl_down(s, off);
        acc[e] = s;
    }
    float score = 0.f;
    if (lane == 0) {
        int be = 0; float bv = acc[0];
        #pragma unroll
        for (int e = 1; e < NEXP; ++e) if (acc[e] > bv) { bv = acc[e]; be = e; }
        score = 1.f / (1.f + __expf(-bv));
        int pos = atomicAdd(&counts[be], 1);
        lists[be * T_TOK + pos] = t;
    }
    score = __shfl(score, 0);
    unsigned short* hbr = hb + (size_t)t * DIM;
    unsigned short* xbr = xb + (size_t)t * DIM;
    #pragma unroll
    for (int i = 0; i < 16; ++i) {
        hbr[lane + 64 * i] = f2bf(hv[i]);
        xbr[lane + 64 * i] = f2bf(score * hv[i]);
    }
}

// ---------------- Kernel 2: grouped gate/up + silu*mul ----------------
// grid: (F/128, T/64, 9). z==8 is the shared expert (all tokens, unscaled h).
// Output H tile (bf16) scattered by token id into Hr (routed) / Hs (shared).
__global__ __launch_bounds__(256) void k_gateup(
    const unsigned short* __restrict__ xb, const unsigned short* __restrict__ hb,
    const float* __restrict__ w_gate, const float* __restrict__ w_up,
    const float* __restrict__ ws_gate, const float* __restrict__ ws_up,
    const int* __restrict__ counts, const int* __restrict__ lists,
    unsigned short* __restrict__ Hr, unsigned short* __restrict__ Hs)
{
    int e = blockIdx.z;
    bool shared_e = (e == NEXP);
    int cnt; const unsigned short* Asrc; const float* Bg; const float* Bu; unsigned short* Out;
    if (shared_e) { cnt = T_TOK; Asrc = hb; Bg = ws_gate; Bu = ws_up; Out = Hs; }
    else {
        cnt = counts[e]; Asrc = xb;
        Bg = w_gate + (size_t)e * DIM * FDIM;
        Bu = w_up   + (size_t)e * DIM * FDIM;
        Out = Hr;
    }
    int row0 = blockIdx.y * 64;
    if (row0 >= cnt) return;
    int col0 = blockIdx.x * 128;

    __shared__ int toks[64];
    __shared__ __align__(16) unsigned short As [64  * BSTRIDE];
    __shared__ __align__(16) unsigned short Bgs[128 * BSTRIDE];
    __shared__ __align__(16) unsigned short Bus[128 * BSTRIDE];

    int tid = threadIdx.x;
    if (tid < 64) {
        int r = row0 + tid;
        toks[tid] = (r < cnt) ? (shared_e ? r : lists[e * T_TOK + r]) : -1;
    }
    __syncthreads();

    int lane = tid & 63, w = tid >> 6;
    int wm = w >> 1, wn = w & 1;
    int arow = tid >> 2, aq = tid & 3;
    int atok = toks[arow];

    floatx4 accg[2][4], accu[2][4];
    #pragma unroll
    for (int mi = 0; mi < 2; ++mi)
    #pragma unroll
    for (int ni = 0; ni < 4; ++ni) {
        floatx4 z = {0.f, 0.f, 0.f, 0.f};
        accg[mi][ni] = z; accu[mi][ni] = z;
    }

    for (int k0 = 0; k0 < DIM; k0 += 32) {
        // stage A (bf16, already converted): 64 rows x 32 k, one uint4 per thread
        uint4 av = make_uint4(0u, 0u, 0u, 0u);
        if (atok >= 0) av = *(const uint4*)(Asrc + (size_t)atok * DIM + k0 + aq * 8);
        *(uint4*)&As[arow * BSTRIDE + aq * 8] = av;
        // stage B gate+up: 32 k x 128 n fp32 -> bf16, transposed to [n][k]
        #pragma unroll
        for (int it = 0; it < 2; ++it) {
            int tt = tid + it * 256;
            int n = tt & 127, kg = tt >> 7;
            const float* pg = Bg + (size_t)(k0 + kg * 8) * FDIM + col0 + n;
            const float* pu = Bu + (size_t)(k0 + kg * 8) * FDIM + col0 + n;
            unsigned int gw[4], uw[4];
            #pragma unroll
            for (int j = 0; j < 4; ++j) {
                gw[j] = (unsigned)f2bf(pg[(size_t)(2*j)*FDIM]) | ((unsigned)f2bf(pg[(size_t)(2*j+1)*FDIM]) << 16);
                uw[j] = (unsigned)f2bf(pu[(size_t)(2*j)*FDIM]) | ((unsigned)f2bf(pu[(size_t)(2*j+1)*FDIM]) << 16);
            }
            *(uint4*)&Bgs[n * BSTRIDE + kg * 8] = make_uint4(gw[0], gw[1], gw[2], gw[3]);
            *(uint4*)&Bus[n * BSTRIDE + kg * 8] = make_uint4(uw[0], uw[1], uw[2], uw[3]);
        }
        __syncthreads();

        int kb = (lane >> 4) * 8;
        short8 a[2], bg[4], bu[4];
        #pragma unroll
        for (int mi = 0; mi < 2; ++mi) {
            int m = wm * 32 + mi * 16 + (lane & 15);
            a[mi] = *(const short8*)&As[m * BSTRIDE + kb];
        }
        #pragma unroll
        for (int ni = 0; ni < 4; ++ni) {
            int n = wn * 64 + ni * 16 + (lane & 15);
            bg[ni] = *(const short8*)&Bgs[n * BSTRIDE + kb];
            bu[ni] = *(const short8*)&Bus[n * BSTRIDE + kb];
        }
        #pragma unroll
        for (int mi = 0; mi < 2; ++mi)
        #pragma unroll
        for (int ni = 0; ni < 4; ++ni) {
            accg[mi][ni] = __builtin_amdgcn_mfma_f32_16x16x32_bf16(a[mi], bg[ni], accg[mi][ni], 0, 0, 0);
            accu[mi][ni] = __builtin_amdgcn_mfma_f32_16x16x32_bf16(a[mi], bu[ni], accu[mi][ni], 0, 0, 0);
        }
        __syncthreads();
    }

    // epilogue: silu(g)*u -> bf16 H, scatter rows by token id
    #pragma unroll
    for (int mi = 0; mi < 2; ++mi)
    #pragma unroll
    for (int ni = 0; ni < 4; ++ni)
    #pragma unroll
    for (int r = 0; r < 4; ++r) {
        int row = wm * 32 + mi * 16 + (lane >> 4) * 4 + r;
        int tok = toks[row];
        if (tok < 0) continue;
        int col = col0 + wn * 64 + ni * 16 + (lane & 15);
        float g = accg[mi][ni][r], u = accu[mi][ni][r];
        float hval = (g / (1.f + __expf(-g))) * u;
        Out[(size_t)tok * FDIM + col] = f2bf(hval);
    }
}

// ---------------- Kernel 3: grouped down-proj, shared fused ----------------
// grid: (D/128, T/64, 8) over routed lists only (top-1 => token partition).
// out[rows] = Hr[rows] @ w_down[e] + Hs[rows] @ ws_down  (fp32 store, no atomics)
__global__ __launch_bounds__(256) void k_down(
    const unsigned short* __restrict__ Hr, const unsigned short* __restrict__ Hs,
    const float* __restrict__ w_down, const float* __restrict__ ws_down,
    const int* __restrict__ counts, const int* __restrict__ lists,
    float* __restrict__ out)
{
    int e = blockIdx.z;
    int cnt = counts[e];
    int row0 = blockIdx.y * 64;
    if (row0 >= cnt) return;
    int col0 = blockIdx.x * 128;
    const float* Bd = w_down + (size_t)e * FDIM * DIM;

    __shared__ int toks[64];
    __shared__ __align__(16) unsigned short Ar [64  * BSTRIDE];
    __shared__ __align__(16) unsigned short Ash[64  * BSTRIDE];
    __shared__ __align__(16) unsigned short Brs[128 * BSTRIDE];
    __shared__ __align__(16) unsigned short Bss[128 * BSTRIDE];

    int tid = threadIdx.x;
    if (tid < 64) {
        int r = row0 + tid;
        toks[tid] = (r < cnt) ? lists[e * T_TOK + r] : -1;
    }
    __syncthreads();

    int lane = tid & 63, w = tid >> 6;
    int wm = w >> 1, wn = w & 1;
    int arow = tid >> 2, aq = tid & 3;
    int atok = toks[arow];

    floatx4 acc[2][4];
    #pragma unroll
    for (int mi = 0; mi < 2; ++mi)
    #pragma unroll
    for (int ni = 0; ni < 4; ++ni) {
        floatx4 z = {0.f, 0.f, 0.f, 0.f};
        acc[mi][ni] = z;
    }

    for (int k0 = 0; k0 < FDIM; k0 += 32) {
        uint4 ar = make_uint4(0u,0u,0u,0u), as = make_uint4(0u,0u,0u,0u);
        if (atok >= 0) {
            ar = *(const uint4*)(Hr + (size_t)atok * FDIM + k0 + aq * 8);
            as = *(const uint4*)(Hs + (size_t)atok * FDIM + k0 + aq * 8);
        }
        *(uint4*)&Ar [arow * BSTRIDE + aq * 8] = ar;
        *(uint4*)&Ash[arow * BSTRIDE + aq * 8] = as;
        #pragma unroll
        for (int it = 0; it < 2; ++it) {
            int tt = tid + it * 256;
            int n = tt & 127, kg = tt >> 7;
            const float* pr = Bd      + (size_t)(k0 + kg * 8) * DIM + col0 + n;
            const float* ps = ws_down + (size_t)(k0 + kg * 8) * DIM + col0 + n;
            unsigned int rw_[4], sw_[4];
            #pragma unroll
            for (int j = 0; j < 4; ++j) {
                rw_[j] = (unsigned)f2bf(pr[(size_t)(2*j)*DIM]) | ((unsigned)f2bf(pr[(size_t)(2*j+1)*DIM]) << 16);
                sw_[j] = (unsigned)f2bf(ps[(size_t)(2*j)*DIM]) | ((unsigned)f2bf(ps[(size_t)(2*j+1)*DIM]) << 16);
            }
            *(uint4*)&Brs[n * BSTRIDE + kg * 8] = make_uint4(rw_[0], rw_[1], rw_[2], rw_[3]);
            *(uint4*)&Bss[n * BSTRIDE + kg * 8] = make_uint4(sw_[0], sw_[1], sw_[2], sw_[3]);
        }
        __syncthreads();

        int kb = (lane >> 4) * 8;
        short8 a1[2], a2[2], b1[4], b2[4];
        #pragma unroll
        for (int mi = 0; mi < 2; ++mi) {
            int m = wm * 32 + mi * 16 + (lane & 15);
            a1[mi] = *(const short8*)&Ar [m * BSTRIDE + kb];
            a2[mi] = *(const short8*)&Ash[m * BSTRIDE + kb];
        }
        #pragma unroll
        for (int ni = 0; ni < 4; ++ni) {
            int n = wn * 64 + ni * 16 + (lane & 15);
            b1[ni] = *(const short8*)&Brs[n * BSTRIDE + kb];
            b2[ni] = *(const short8*)&Bss[n * BSTRIDE + kb];
        }
        #pragma unroll
        for (int mi = 0; mi < 2; ++mi)
        #pragma unroll
        for (int ni = 0; ni < 4; ++ni) {
            acc[mi][ni] = __builtin_amdgcn_mfma_f32_16x16x32_bf16(a1[mi], b1[ni], acc[mi][ni], 0, 0, 0);
            acc[mi][ni] = __builtin_amdgcn_mfma_f32_16x16x32_bf16(a2[mi], b2[ni], acc[mi][ni], 0, 0, 0);
        }
        __syncthreads();
    }

    #pragma unroll
    for (int mi = 0; mi < 2; ++mi)
    #pragma unroll
    for (int ni = 0; ni < 4; ++ni)
    #pragma unroll
    for (int r = 0; r < 4; ++r) {
        int row = wm * 32 + mi * 16 + (lane >> 4) * 4 + r;
        int tok = toks[row];
        if (tok < 0) continue;
        int col = col0 + wn * 64 + ni * 16 + (lane & 15);
        out[(size_t)tok * DIM + col] = acc[mi][ni][r];
    }
}

extern "C" void kernel_launch(void* const* d_in, const int* in_sizes, int n_in,
                              void* d_out, int out_size, void* d_ws, size_t ws_size,
                              hipStream_t stream)
{
    const float* h   = (const float*)d_in[0];
    const float* rw  = (const float*)d_in[1];
    const float* wg  = (const float*)d_in[2];
    const float* wu  = (const float*)d_in[3];
    const float* wd  = (const float*)d_in[4];
    const float* wsg = (const float*)d_in[5];
    const float* wsu = (const float*)d_in[6];
    const float* wsd = (const float*)d_in[7];
    float* out = (float*)d_out;

    char* ws = (char*)d_ws;
    int* counts = (int*)ws;                                   // 16 ints (use 8)
    int* lists  = (int*)(ws + 1024);                          // [E][T] ints = 64 KB
    unsigned short* hb = (unsigned short*)(ws + 131072);      // [T][D] bf16 = 4 MB
    unsigned short* xb = hb + (size_t)T_TOK * DIM;            // [T][D] bf16 = 4 MB
    unsigned short* Hr = xb + (size_t)T_TOK * DIM;            // [T][F] bf16 = 8 MB
    unsigned short* Hs = Hr + (size_t)T_TOK * FDIM;           // [T][F] bf16 = 8 MB

    hipMemsetAsync(counts, 0, 64, stream);
    k_router<<<dim3(T_TOK / 4), 256, 0, stream>>>(h, rw, counts, lists, hb, xb);
    k_gateup<<<dim3(FDIM / 128, T_TOK / 64, NEXP + 1), 256, 0, stream>>>(
        xb, hb, wg, wu, wsg, wsu, counts, lists, Hr, Hs);
    k_down<<<dim3(DIM / 128, T_TOK / 64, NEXP), 256, 0, stream>>>(
        Hr, Hs, wd, wsd, counts, lists, out);
}

// Round 2
// 415.928 us; speedup vs baseline: 1.1975x; 1.1975x over previous
//
#include <hip/hip_runtime.h>
#include <hip/hip_bf16.h>
#include <cstdint>
#include <cstddef>

#define T_TOK 2048
#define DIM   1024
#define FDIM  2048
#define NEXP  8
#define BSTRIDE 40   // LDS row stride (bf16) for 32-k tiles, padded vs bank conflicts

#define GU_MAX 96    // sum ceil(cnt_e/64) <= 40, + 32 shared tiles = 72 max
#define DN_MAX 96    // <= 40 tiles * 2 K-splits = 80 max

typedef short  short8  __attribute__((ext_vector_type(8)));
typedef float  floatx4 __attribute__((ext_vector_type(4)));

__device__ inline unsigned short f2bf(float f) {
    unsigned int u = __builtin_bit_cast(unsigned int, f);
    unsigned int r = (u + 0x7FFFu + ((u >> 16) & 1u)) >> 16;  // RNE
    return (unsigned short)r;
}

// ---------------- Kernel 1: router + bf16 prep ----------------
__global__ __launch_bounds__(256) void k_router(
    const float* __restrict__ h, const float* __restrict__ rw,
    int* __restrict__ counts, int* __restrict__ lists,
    unsigned short* __restrict__ hb, unsigned short* __restrict__ xb)
{
    int w = threadIdx.x >> 6, lane = threadIdx.x & 63;
    int t = blockIdx.x * 4 + w;
    const float* hrow = h + (size_t)t * DIM;
    float hv[16];
    #pragma unroll
    for (int i = 0; i < 16; ++i) hv[i] = hrow[lane + 64 * i];
    float acc[NEXP];
    #pragma unroll
    for (int e = 0; e < NEXP; ++e) {
        const float* r = rw + (size_t)e * DIM;
        float s = 0.f;
        #pragma unroll
        for (int i = 0; i < 16; ++i) s += hv[i] * r[lane + 64 * i];
        acc[e] = s;
    }
    #pragma unroll
    for (int e = 0; e < NEXP; ++e) {
        float s = acc[e];
        for (int off = 32; off > 0; off >>= 1) s += __shfl_down(s, off);
        acc[e] = s;
    }
    float score = 0.f;
    if (lane == 0) {
        int be = 0; float bv = acc[0];
        #pragma unroll
        for (int e = 1; e < NEXP; ++e) if (acc[e] > bv) { bv = acc[e]; be = e; }
        score = 1.f / (1.f + __expf(-bv));
        int pos = atomicAdd(&counts[be], 1);
        lists[be * T_TOK + pos] = t;
    }
    score = __shfl(score, 0);
    unsigned short* hbr = hb + (size_t)t * DIM;
    unsigned short* xbr = xb + (size_t)t * DIM;
    #pragma unroll
    for (int i = 0; i < 16; ++i) {
        hbr[lane + 64 * i] = f2bf(hv[i]);
        xbr[lane + 64 * i] = f2bf(score * hv[i]);
    }
}

// ---------------- Kernel 1b: compact tile scheduler ----------------
// Builds contiguous work lists so active GEMM blocks spread across all CUs.
__global__ void k_schedule(const int* __restrict__ counts,
                           int* __restrict__ gu, int* __restrict__ dn)
{
    if (threadIdx.x != 0 || blockIdx.x != 0) return;
    int n = 0;
    for (int e = 0; e < NEXP; ++e) {
        int c = counts[e];
        for (int r = 0; r < c; r += 64) gu[n++] = (e << 16) | r;
    }
    for (int r = 0; r < T_TOK; r += 64) gu[n++] = (NEXP << 16) | r;
    while (n < GU_MAX) gu[n++] = -1;
    n = 0;
    for (int e = 0; e < NEXP; ++e) {
        int c = counts[e];
        for (int r = 0; r < c; r += 64) {
            dn[n++] = (e << 16) | r;               // ks=0: routed half
            dn[n++] = (1 << 28) | (e << 16) | r;   // ks=1: shared half
        }
    }
    while (n < DN_MAX) dn[n++] = -1;
}

// ---------------- Kernel 2: grouped gate/up + silu*mul -> Hc ----------------
// grid (16 col-tiles, GU_MAX). Entry packs (e, row0); e==8 -> shared expert.
// Hc layout: [T][2*FDIM] bf16: cols 0..2047 routed product, 2048..4095 shared.
__global__ __launch_bounds__(256) void k_gateup(
    const unsigned short* __restrict__ xb, const unsigned short* __restrict__ hb,
    const float* __restrict__ w_gate, const float* __restrict__ w_up,
    const float* __restrict__ ws_gate, const float* __restrict__ ws_up,
    const int* __restrict__ counts, const int* __restrict__ lists,
    const int* __restrict__ gu_tiles, unsigned short* __restrict__ Hc)
{
    int ent = gu_tiles[blockIdx.y];
    if (ent < 0) return;
    int e = ent >> 16, row0 = ent & 0xffff;
    bool sh = (e == NEXP);
    int cnt = sh ? T_TOK : counts[e];
    const unsigned short* Asrc = sh ? hb : xb;
    const float* Bg = sh ? ws_gate : w_gate + (size_t)e * DIM * FDIM;
    const float* Bu = sh ? ws_up   : w_up   + (size_t)e * DIM * FDIM;
    int outoff = sh ? FDIM : 0;
    int col0 = blockIdx.x * 128;

    __shared__ int toks[64];
    __shared__ __align__(16) unsigned short As [64  * BSTRIDE];
    __shared__ __align__(16) unsigned short Bgs[128 * BSTRIDE];
    __shared__ __align__(16) unsigned short Bus[128 * BSTRIDE];

    int tid = threadIdx.x;
    if (tid < 64) {
        int r = row0 + tid;
        toks[tid] = (r < cnt) ? (sh ? r : lists[e * T_TOK + r]) : -1;
    }
    __syncthreads();

    int lane = tid & 63, w = tid >> 6;
    int wm = w >> 1, wn = w & 1;
    int arow = tid >> 2, aq = tid & 3;
    int atok = toks[arow];

    floatx4 accg[2][4], accu[2][4];
    #pragma unroll
    for (int mi = 0; mi < 2; ++mi)
    #pragma unroll
    for (int ni = 0; ni < 4; ++ni) {
        floatx4 z = {0.f, 0.f, 0.f, 0.f};
        accg[mi][ni] = z; accu[mi][ni] = z;
    }

    uint4 pa;
    float gr[2][8], ur[2][8];
    auto prefetch = [&](int k0) {
        pa = make_uint4(0u, 0u, 0u, 0u);
        if (atok >= 0) pa = *(const uint4*)(Asrc + (size_t)atok * DIM + k0 + aq * 8);
        #pragma unroll
        for (int it = 0; it < 2; ++it) {
            int tt = tid + it * 256;
            int n = tt & 127, kg = tt >> 7;
            const float* pg = Bg + (size_t)(k0 + kg * 8) * FDIM + col0 + n;
            const float* pu = Bu + (size_t)(k0 + kg * 8) * FDIM + col0 + n;
            #pragma unroll
            for (int j = 0; j < 8; ++j) {
                gr[it][j] = pg[(size_t)j * FDIM];
                ur[it][j] = pu[(size_t)j * FDIM];
            }
        }
    };
    auto commit = [&]() {
        *(uint4*)&As[arow * BSTRIDE + aq * 8] = pa;
        #pragma unroll
        for (int it = 0; it < 2; ++it) {
            int tt = tid + it * 256;
            int n = tt & 127, kg = tt >> 7;
            unsigned int gw[4], uw[4];
            #pragma unroll
            for (int j = 0; j < 4; ++j) {
                gw[j] = (unsigned)f2bf(gr[it][2*j]) | ((unsigned)f2bf(gr[it][2*j+1]) << 16);
                uw[j] = (unsigned)f2bf(ur[it][2*j]) | ((unsigned)f2bf(ur[it][2*j+1]) << 16);
            }
            *(uint4*)&Bgs[n * BSTRIDE + kg * 8] = make_uint4(gw[0], gw[1], gw[2], gw[3]);
            *(uint4*)&Bus[n * BSTRIDE + kg * 8] = make_uint4(uw[0], uw[1], uw[2], uw[3]);
        }
    };

    prefetch(0);
    for (int k0 = 0; k0 < DIM; k0 += 32) {
        __syncthreads();
        commit();
        if (k0 + 32 < DIM) prefetch(k0 + 32);
        __syncthreads();

        int kb = (lane >> 4) * 8;
        short8 a[2], bg[4], bu[4];
        #pragma unroll
        for (int mi = 0; mi < 2; ++mi) {
            int m = wm * 32 + mi * 16 + (lane & 15);
            a[mi] = *(const short8*)&As[m * BSTRIDE + kb];
        }
        #pragma unroll
        for (int ni = 0; ni < 4; ++ni) {
            int n = wn * 64 + ni * 16 + (lane & 15);
            bg[ni] = *(const short8*)&Bgs[n * BSTRIDE + kb];
            bu[ni] = *(const short8*)&Bus[n * BSTRIDE + kb];
        }
        #pragma unroll
        for (int mi = 0; mi < 2; ++mi)
        #pragma unroll
        for (int ni = 0; ni < 4; ++ni) {
            accg[mi][ni] = __builtin_amdgcn_mfma_f32_16x16x32_bf16(a[mi], bg[ni], accg[mi][ni], 0, 0, 0);
            accu[mi][ni] = __builtin_amdgcn_mfma_f32_16x16x32_bf16(a[mi], bu[ni], accu[mi][ni], 0, 0, 0);
        }
    }

    #pragma unroll
    for (int mi = 0; mi < 2; ++mi)
    #pragma unroll
    for (int ni = 0; ni < 4; ++ni)
    #pragma unroll
    for (int r = 0; r < 4; ++r) {
        int row = wm * 32 + mi * 16 + (lane >> 4) * 4 + r;
        int tok = toks[row];
        if (tok < 0) continue;
        int col = col0 + wn * 64 + ni * 16 + (lane & 15);
        float g = accg[mi][ni][r], u = accu[mi][ni][r];
        float hval = (g / (1.f + __expf(-g))) * u;
        Hc[(size_t)tok * (2 * FDIM) + outoff + col] = f2bf(hval);
    }
}

// ---------------- Kernel 3: down-proj, split-K=2, atomic accumulate ----------
// grid (8 col-tiles, DN_MAX). ks=0: Hc[:,0:2048] @ w_down[e]; ks=1:
// Hc[:,2048:4096] @ ws_down. out zero-initialized; fp32 atomicAdd epilogue.
__global__ __launch_bounds__(256) void k_down(
    const unsigned short* __restrict__ Hc,
    const float* __restrict__ w_down, const float* __restrict__ ws_down,
    const int* __restrict__ counts, const int* __restrict__ lists,
    const int* __restrict__ dn_tiles, float* __restrict__ out)
{
    int ent = dn_tiles[blockIdx.y];
    if (ent < 0) return;
    int ks = (ent >> 28) & 1, e = (ent >> 16) & 0xff, row0 = ent & 0xffff;
    int cnt = counts[e];
    const float* B = ks ? ws_down : w_down + (size_t)e * FDIM * DIM;
    int col0 = blockIdx.x * 128;

    __shared__ int toks[64];
    __shared__ __align__(16) unsigned short As[64  * BSTRIDE];
    __shared__ __align__(16) unsigned short Bs[128 * BSTRIDE];

    int tid = threadIdx.x;
    if (tid < 64) {
        int r = row0 + tid;
        toks[tid] = (r < cnt) ? lists[e * T_TOK + r] : -1;
    }
    __syncthreads();

    int lane = tid & 63, w = tid >> 6;
    int wm = w >> 1, wn = w & 1;
    int arow = tid >> 2, aq = tid & 3;
    int atok = toks[arow];
    size_t abase = (size_t)ks * FDIM;  // column offset into Hc row

    floatx4 acc[2][4];
    #pragma unroll
    for (int mi = 0; mi < 2; ++mi)
    #pragma unroll
    for (int ni = 0; ni < 4; ++ni) {
        floatx4 z = {0.f, 0.f, 0.f, 0.f};
        acc[mi][ni] = z;
    }

    uint4 pa;
    float br[2][8];
    auto prefetch = [&](int k0) {
        pa = make_uint4(0u, 0u, 0u, 0u);
        if (atok >= 0)
            pa = *(const uint4*)(Hc + (size_t)atok * (2 * FDIM) + abase + k0 + aq * 8);
        #pragma unroll
        for (int it = 0; it < 2; ++it) {
            int tt = tid + it * 256;
            int n = tt & 127, kg = tt >> 7;
            const float* pb = B + (size_t)(k0 + kg * 8) * DIM + col0 + n;
            #pragma unroll
            for (int j = 0; j < 8; ++j) br[it][j] = pb[(size_t)j * DIM];
        }
    };
    auto commit = [&]() {
        *(uint4*)&As[arow * BSTRIDE + aq * 8] = pa;
        #pragma unroll
        for (int it = 0; it < 2; ++it) {
            int tt = tid + it * 256;
            int n = tt & 127, kg = tt >> 7;
            unsigned int bw[4];
            #pragma unroll
            for (int j = 0; j < 4; ++j)
                bw[j] = (unsigned)f2bf(br[it][2*j]) | ((unsigned)f2bf(br[it][2*j+1]) << 16);
            *(uint4*)&Bs[n * BSTRIDE + kg * 8] = make_uint4(bw[0], bw[1], bw[2], bw[3]);
        }
    };

    prefetch(0);
    for (int k0 = 0; k0 < FDIM; k0 += 32) {
        __syncthreads();
        commit();
        if (k0 + 32 < FDIM) prefetch(k0 + 32);
        __syncthreads();

        int kb = (lane >> 4) * 8;
        short8 a[2], b[4];
        #pragma unroll
        for (int mi = 0; mi < 2; ++mi) {
            int m = wm * 32 + mi * 16 + (lane & 15);
            a[mi] = *(const short8*)&As[m * BSTRIDE + kb];
        }
        #pragma unroll
        for (int ni = 0; ni < 4; ++ni) {
            int n = wn * 64 + ni * 16 + (lane & 15);
            b[ni] = *(const short8*)&Bs[n * BSTRIDE + kb];
        }
        #pragma unroll
        for (int mi = 0; mi < 2; ++mi)
        #pragma unroll
        for (int ni = 0; ni < 4; ++ni)
            acc[mi][ni] = __builtin_amdgcn_mfma_f32_16x16x32_bf16(a[mi], b[ni], acc[mi][ni], 0, 0, 0);
    }

    #pragma unroll
    for (int mi = 0; mi < 2; ++mi)
    #pragma unroll
    for (int ni = 0; ni < 4; ++ni)
    #pragma unroll
    for (int r = 0; r < 4; ++r) {
        int row = wm * 32 + mi * 16 + (lane >> 4) * 4 + r;
        int tok = toks[row];
        if (tok < 0) continue;
        int col = col0 + wn * 64 + ni * 16 + (lane & 15);
        atomicAdd(&out[(size_t)tok * DIM + col], acc[mi][ni][r]);
    }
}

extern "C" void kernel_launch(void* const* d_in, const int* in_sizes, int n_in,
                              void* d_out, int out_size, void* d_ws, size_t ws_size,
                              hipStream_t stream)
{
    const float* h   = (const float*)d_in[0];
    const float* rw  = (const float*)d_in[1];
    const float* wg  = (const float*)d_in[2];
    const float* wu  = (const float*)d_in[3];
    const float* wd  = (const float*)d_in[4];
    const float* wsg = (const float*)d_in[5];
    const float* wsu = (const float*)d_in[6];
    const float* wsd = (const float*)d_in[7];
    float* out = (float*)d_out;

    char* ws = (char*)d_ws;
    int* counts   = (int*)ws;                                 // 64 B
    int* gu_tiles = (int*)(ws + 256);                         // 96 ints
    int* dn_tiles = (int*)(ws + 1024);                        // 96 ints
    int* lists    = (int*)(ws + 2048);                        // [E][T] = 64 KB
    unsigned short* hb = (unsigned short*)(ws + 131072);      // [T][D] bf16 = 4 MB
    unsigned short* xb = hb + (size_t)T_TOK * DIM;            // [T][D] bf16 = 4 MB
    unsigned short* Hc = xb + (size_t)T_TOK * DIM;            // [T][2F] bf16 = 16 MB

    hipMemsetAsync(counts, 0, 64, stream);
    hipMemsetAsync(out, 0, (size_t)T_TOK * DIM * sizeof(float), stream);
    k_router<<<dim3(T_TOK / 4), 256, 0, stream>>>(h, rw, counts, lists, hb, xb);
    k_schedule<<<dim3(1), 64, 0, stream>>>(counts, gu_tiles, dn_tiles);
    k_gateup<<<dim3(FDIM / 128, GU_MAX), 256, 0, stream>>>(
        xb, hb, wg, wu, wsg, wsu, counts, lists, gu_tiles, Hc);
    k_down<<<dim3(DIM / 128, DN_MAX), 256, 0, stream>>>(
        Hc, wd, wsd, counts, lists, dn_tiles, out);
}